// Round 8
// baseline (73.902 us; speedup 1.0000x reference)
//
#include <hip/hip_runtime.h>

#define NB   4
#define SEQ  4096
#define CIN  128
#define C4D  32
#define OUTC 128

typedef __attribute__((ext_vector_type(8))) short bf16x8;
typedef __attribute__((ext_vector_type(4))) float f32x4;

__device__ __forceinline__ short f2bf(float f) {
  union { float f; unsigned u; } v; v.f = f;
  unsigned r = v.u + 0x7FFFu + ((v.u >> 16) & 1u);
  return (short)(r >> 16);
}

__device__ __forceinline__ unsigned cvt_pk_bf16(float lo, float hi) {
  unsigned r;
  asm("v_cvt_pk_bf16_f32 %0, %1, %2" : "=v"(r) : "v"(lo), "v"(hi));
  return r;
}

__device__ __forceinline__ f32x4 mfma16(bf16x8 a, bf16x8 b, f32x4 c) {
  return __builtin_amdgcn_mfma_f32_16x16x32_bf16(a, b, c, 0, 0, 0);
}

// ---------------------------------------------------------------------------
// Kernel 1: fold value-path weights (unchanged).
// ---------------------------------------------------------------------------
__global__ void k_fuse(const float* __restrict__ wq, const float* __restrict__ wk,
                       const float* __restrict__ wv, const float* __restrict__ weight,
                       const float* __restrict__ bv,
                       short* __restrict__ wqb, short* __restrict__ wkb,
                       short* __restrict__ wfT, float* __restrict__ bfu) {
  int u = blockIdx.x, c = threadIdx.x;
  float acc = 0.f;
  for (int o = 0; o < OUTC; ++o) acc += wv[o * CIN + c] * weight[o * OUTC + u];
  wfT[u * CIN + c] = f2bf(acc);
  if (u < C4D) {
    wqb[u * CIN + c] = f2bf(wq[u * CIN + c]);
    wkb[u * CIN + c] = f2bf(wk[u * CIN + c]);
  }
  if (c == 0) {
    float a = 0.f;
    for (int o = 0; o < OUTC; ++o) a += bv[o] * weight[o * OUTC + u];
    bfu[u] = a;
  }
}

// ---------------------------------------------------------------------------
// Kernel 2: projections. Fragment-linear QL / VF tiles; VF stores vectorized
// (uint2 of 4 packed bf16 — r=0..3 are contiguous in the VF layout).
// ---------------------------------------------------------------------------
__global__ __launch_bounds__(256) void k_proj(
    const float* __restrict__ x, const float* __restrict__ bq, const float* __restrict__ bk,
    const short* __restrict__ wqb, const short* __restrict__ wkb,
    const short* __restrict__ wfT, const float* __restrict__ bfu,
    short* __restrict__ ql, short* __restrict__ kb, short* __restrict__ vfb) {
  const int wid = threadIdx.x >> 6, lane = threadIdx.x & 63;
  const int lo = lane & 15, g = lane >> 4;
  const int p0 = blockIdx.x * 64 + wid * 16;

  f32x4 aq[2] = {}, ak[2] = {}, as_[8] = {};

#pragma unroll
  for (int kk = 0; kk < 4; ++kk) {
    const float* xp = x + (size_t)(p0 + lo) * CIN + kk * 32 + g * 8;
    float4 xa = *(const float4*)xp;
    float4 xb = *(const float4*)(xp + 4);
    bf16x8 af;
    af[0] = f2bf(xa.x); af[1] = f2bf(xa.y); af[2] = f2bf(xa.z); af[3] = f2bf(xa.w);
    af[4] = f2bf(xb.x); af[5] = f2bf(xb.y); af[6] = f2bf(xb.z); af[7] = f2bf(xb.w);
#pragma unroll
    for (int n = 0; n < 2; ++n) {
      bf16x8 bq_ = *(const bf16x8*)(wqb + (size_t)(n * 16 + lo) * CIN + kk * 32 + g * 8);
      aq[n] = mfma16(af, bq_, aq[n]);
      bf16x8 bk_ = *(const bf16x8*)(wkb + (size_t)(n * 16 + lo) * CIN + kk * 32 + g * 8);
      ak[n] = mfma16(af, bk_, ak[n]);
    }
#pragma unroll
    for (int n = 0; n < 8; ++n) {
      bf16x8 bs = *(const bf16x8*)(wfT + (size_t)(n * 16 + lo) * CIN + kk * 32 + g * 8);
      as_[n] = mfma16(af, bs, as_[n]);
    }
  }

#pragma unroll
  for (int n = 0; n < 2; ++n) {
    float bqv = bq[n * 16 + lo], bkv = bk[n * 16 + lo];
    int u = n * 16 + lo;
#pragma unroll
    for (int r = 0; r < 4; ++r) {
      int p = p0 + 4 * g + r;
      int bb = p >> 12, s = p & (SEQ - 1);
      ql[(size_t)bb * (SEQ * 32) + (size_t)(s >> 5) * 1024 + ((s >> 4) & 1) * 512 +
         (u >> 3) * 128 + (s & 15) * 8 + (u & 7)] = f2bf(aq[n][r] + bqv);
      kb[(size_t)p * C4D + u] = f2bf(ak[n][r] + bkv);
    }
  }
  {
    const int p = p0 + 4 * g;          // r = 0; r=0..3 contiguous in VF
    const int bb = p >> 12, s = p & (SEQ - 1);
#pragma unroll
    for (int n = 0; n < 8; ++n) {
      int u = n * 16 + lo;
      float bvv = bfu[u];
      uint2 w;
      w.x = cvt_pk_bf16(as_[n][0] + bvv, as_[n][1] + bvv);
      w.y = cvt_pk_bf16(as_[n][2] + bvv, as_[n][3] + bvv);
      *(uint2*)&vfb[(size_t)bb * (SEQ * 128) + (size_t)(s >> 5) * 4096 + (u >> 4) * 512 +
                    ((s >> 2) & 3) * 128 + (u & 15) * 8 + ((s >> 4) & 1) * 4] = w;
    }
  }
}

// ---------------------------------------------------------------------------
// Kernel 3: attention, two-pass branchless. Block = 8 waves, 32 i-rows; wave
// owns j-eighth. Pass 1: exact row max (QK only). Pass 2: rescale-free
// softmax + PV, unrolled 2x for load/compute overlap. XCD-swizzled blockIdx.
// Tree merge via 2 LDS slots (proven R7 math).
// ---------------------------------------------------------------------------
__global__ __launch_bounds__(512, 4) void k_attn(
    const short* __restrict__ ql, const short* __restrict__ kb,
    const short* __restrict__ vfb, const float* __restrict__ bias,
    float* __restrict__ out) {
  const int tid = threadIdx.x;
  const int wid = tid >> 6, lane = tid & 63;
  const int lo = lane & 15, g = lane >> 4;
  const int bid = blockIdx.x;
  const int xb = ((bid & 7) << 6) | (bid >> 3);   // 512 blocks -> 8 XCD chunks
  const int b = xb >> 7;
  const int iw = (xb & 127) * 32;

  __shared__ float OS[2][4096];
  __shared__ float MS[2][32], LS[2][32];

  const short* qB = ql + (size_t)b * (SEQ * 32) + (size_t)wid * 16384;
  const short* vB = vfb + (size_t)b * (SEQ * 128) + (size_t)wid * 65536;

  bf16x8 kf0 = *(const bf16x8*)(kb + (size_t)(b * SEQ + iw + lo) * C4D + g * 8);
  bf16x8 kf1 = *(const bf16x8*)(kb + (size_t)(b * SEQ + iw + 16 + lo) * C4D + g * 8);

  const f32x4 zf = {0.f, 0.f, 0.f, 0.f};

  // ---- pass 1: exact per-row max over this wave's j-range ----
  f32x4 mva = {-3e38f, -3e38f, -3e38f, -3e38f};
  f32x4 mvb = {-3e38f, -3e38f, -3e38f, -3e38f};
#pragma unroll 2
  for (int t = 0; t < 16; ++t) {
    const short* qt = qB + t * 1024;
    bf16x8 qf0 = *(const bf16x8*)(qt + lane * 8);
    bf16x8 qf1 = *(const bf16x8*)(qt + 512 + lane * 8);
    f32x4 sa0 = mfma16(qf0, kf0, zf);
    f32x4 sa1 = mfma16(qf1, kf0, zf);
    f32x4 sb0 = mfma16(qf0, kf1, zf);
    f32x4 sb1 = mfma16(qf1, kf1, zf);
#pragma unroll
    for (int r = 0; r < 4; ++r) {
      mva[r] = fmaxf(mva[r], fmaxf(sa0[r], sa1[r]));
      mvb[r] = fmaxf(mvb[r], fmaxf(sb0[r], sb1[r]));
    }
  }
  float ma = fmaxf(fmaxf(mva[0], mva[1]), fmaxf(mva[2], mva[3]));
  ma = fmaxf(ma, __shfl_xor(ma, 16, 64));
  ma = fmaxf(ma, __shfl_xor(ma, 32, 64));
  float mb_ = fmaxf(fmaxf(mvb[0], mvb[1]), fmaxf(mvb[2], mvb[3]));
  mb_ = fmaxf(mb_, __shfl_xor(mb_, 16, 64));
  mb_ = fmaxf(mb_, __shfl_xor(mb_, 32, 64));

  // ---- pass 2: branchless softmax + PV ----
  f32x4 oa[8] = {}, ob[8] = {};
  float la = 0.f, lb = 0.f;
#pragma unroll 2
  for (int t = 0; t < 16; ++t) {
    const short* qt = qB + t * 1024;
    bf16x8 qf0 = *(const bf16x8*)(qt + lane * 8);
    bf16x8 qf1 = *(const bf16x8*)(qt + 512 + lane * 8);
    f32x4 sa0 = mfma16(qf0, kf0, zf);
    f32x4 sa1 = mfma16(qf1, kf0, zf);
    f32x4 sb0 = mfma16(qf0, kf1, zf);
    f32x4 sb1 = mfma16(qf1, kf1, zf);

    float pa[8], pb[8];
#pragma unroll
    for (int r = 0; r < 4; ++r) {
      pa[r] = __expf(sa0[r] - ma); pa[4 + r] = __expf(sa1[r] - ma);
      pb[r] = __expf(sb0[r] - mb_); pb[4 + r] = __expf(sb1[r] - mb_);
    }
    la += (pa[0] + pa[1]) + (pa[2] + pa[3]) + ((pa[4] + pa[5]) + (pa[6] + pa[7]));
    lb += (pb[0] + pb[1]) + (pb[2] + pb[3]) + ((pb[4] + pb[5]) + (pb[6] + pb[7]));

    union { bf16x8 v8; unsigned u[4]; } ka, kb2;
    ka.u[0] = cvt_pk_bf16(pa[0], pa[1]); ka.u[1] = cvt_pk_bf16(pa[2], pa[3]);
    ka.u[2] = cvt_pk_bf16(pa[4], pa[5]); ka.u[3] = cvt_pk_bf16(pa[6], pa[7]);
    kb2.u[0] = cvt_pk_bf16(pb[0], pb[1]); kb2.u[1] = cvt_pk_bf16(pb[2], pb[3]);
    kb2.u[2] = cvt_pk_bf16(pb[4], pb[5]); kb2.u[3] = cvt_pk_bf16(pb[6], pb[7]);
    bf16x8 pfa = ka.v8, pfb = kb2.v8;

    const short* vt = vB + t * 4096;
#pragma unroll
    for (int n = 0; n < 8; ++n) {
      bf16x8 vfr = *(const bf16x8*)(vt + n * 512 + lane * 8);
      oa[n] = mfma16(pfa, vfr, oa[n]);
      ob[n] = mfma16(pfb, vfr, ob[n]);
    }
  }

  // deferred l-reduce over g-groups (each g covers distinct j)
  la += __shfl_xor(la, 16, 64); la += __shfl_xor(la, 32, 64);
  lb += __shfl_xor(lb, 16, 64); lb += __shfl_xor(lb, 32, 64);

  auto write_slot = [&](int s) {
#pragma unroll
    for (int n = 0; n < 8; ++n) {
      *(f32x4*)&OS[s][n * 256 + lane * 4] = oa[n];
      *(f32x4*)&OS[s][(8 + n) * 256 + lane * 4] = ob[n];
    }
    if (lane < 16) {
      MS[s][lo] = ma; MS[s][16 + lo] = mb_;
      LS[s][lo] = la; LS[s][16 + lo] = lb;
    }
  };
  auto merge_slot = [&](int s) {
    float msa = MS[s][lo], msb = MS[s][16 + lo];
    float lsa = LS[s][lo], lsb = LS[s][16 + lo];
    float Ma = fmaxf(ma, msa), Mb = fmaxf(mb_, msb);
    float eoa = __expf(ma - Ma), esa = __expf(msa - Ma);
    float eob = __expf(mb_ - Mb), esb = __expf(msb - Mb);
    la = eoa * la + esa * lsa; lb = eob * lb + esb * lsb;
    ma = Ma; mb_ = Mb;
    float eoar[4], esar[4], eobr[4], esbr[4];
#pragma unroll
    for (int r = 0; r < 4; ++r) {
      int src = 4 * g + r;
      eoar[r] = __shfl(eoa, src, 64); esar[r] = __shfl(esa, src, 64);
      eobr[r] = __shfl(eob, src, 64); esbr[r] = __shfl(esb, src, 64);
    }
#pragma unroll
    for (int n = 0; n < 8; ++n) {
      f32x4 va = *(f32x4*)&OS[s][n * 256 + lane * 4];
      f32x4 vb = *(f32x4*)&OS[s][(8 + n) * 256 + lane * 4];
#pragma unroll
      for (int r = 0; r < 4; ++r) {
        oa[n][r] = eoar[r] * oa[n][r] + esar[r] * va[r];
        ob[n][r] = eobr[r] * ob[n][r] + esbr[r] * vb[r];
      }
    }
  };

  if (wid == 1) write_slot(0);
  if (wid == 3) write_slot(1);
  __syncthreads();
  if (wid == 0) merge_slot(0);
  if (wid == 2) merge_slot(1);
  __syncthreads();
  if (wid == 5) write_slot(0);
  if (wid == 7) write_slot(1);
  __syncthreads();
  if (wid == 4) merge_slot(0);
  if (wid == 6) merge_slot(1);
  __syncthreads();
  if (wid == 2) write_slot(0);
  if (wid == 6) write_slot(1);
  __syncthreads();
  if (wid == 0) merge_slot(0);
  if (wid == 4) merge_slot(1);
  __syncthreads();
  if (wid == 4) write_slot(0);
  __syncthreads();
  if (wid == 0) {
    merge_slot(0);
    float lia[4], lib[4];
    float ia = 1.f / la, ib = 1.f / lb;
#pragma unroll
    for (int r = 0; r < 4; ++r) {
      int src = 4 * g + r;
      lia[r] = __shfl(ia, src, 64);
      lib[r] = __shfl(ib, src, 64);
    }
    float* outp = out + (size_t)(b * SEQ + iw) * OUTC;
#pragma unroll
    for (int n = 0; n < 8; ++n) {
      float bu = bias[n * 16 + lo];
#pragma unroll
      for (int r = 0; r < 4; ++r) {
        outp[(size_t)(4 * g + r) * OUTC + n * 16 + lo] = oa[n][r] * lia[r] + bu;
        outp[(size_t)(16 + 4 * g + r) * OUTC + n * 16 + lo] = ob[n][r] * lib[r] + bu;
      }
    }
  }
}

// ---------------------------------------------------------------------------
extern "C" void kernel_launch(void* const* d_in, const int* in_sizes, int n_in,
                              void* d_out, int out_size, void* d_ws, size_t ws_size,
                              hipStream_t stream) {
  (void)in_sizes; (void)n_in; (void)out_size; (void)ws_size;
  const float* x      = (const float*)d_in[0];
  const float* weight = (const float*)d_in[1];
  const float* bias   = (const float*)d_in[2];
  const float* wq     = (const float*)d_in[3];
  const float* bq     = (const float*)d_in[4];
  const float* wk     = (const float*)d_in[5];
  const float* bk     = (const float*)d_in[6];
  const float* wv     = (const float*)d_in[7];
  const float* bv     = (const float*)d_in[8];
  float* out = (float*)d_out;

  char* ws = (char*)d_ws;
  short* kbuf = (short*)(ws);                                   // 1 MiB [p][32]
  short* vfb  = (short*)(ws + ((size_t)1 << 20));               // 4 MiB VF tiles
  short* qlb  = (short*)(ws + ((size_t)5 << 20));               // 1 MiB QL tiles
  short* wqb  = (short*)(ws + ((size_t)6 << 20));               // 8 KiB
  short* wkb  = (short*)(ws + ((size_t)6 << 20) + 8192);        // 8 KiB
  short* wfT  = (short*)(ws + ((size_t)6 << 20) + 16384);       // 32 KiB
  float* bfu  = (float*)(ws + ((size_t)6 << 20) + 49152);       // 512 B

  hipLaunchKernelGGL(k_fuse, dim3(OUTC), dim3(CIN), 0, stream,
                     wq, wk, wv, weight, bv, wqb, wkb, wfT, bfu);
  hipLaunchKernelGGL(k_proj, dim3(NB * SEQ / 64), dim3(256), 0, stream,
                     x, bq, bk, wqb, wkb, wfT, bfu, qlb, kbuf, vfb);
  hipLaunchKernelGGL(k_attn, dim3(NB * SEQ / 32), dim3(512), 0, stream,
                     qlb, kbuf, vfb, bias, out);
}

// Round 9
// 61.323 us; speedup vs baseline: 1.2051x; 1.2051x over previous
//
#include <hip/hip_runtime.h>

#define NB   4
#define SEQ  4096
#define CIN  128
#define C4D  32
#define OUTC 128

typedef __attribute__((ext_vector_type(8))) short bf16x8;
typedef __attribute__((ext_vector_type(4))) float f32x4;

__device__ __forceinline__ short f2bf(float f) {
  union { float f; unsigned u; } v; v.f = f;
  unsigned r = v.u + 0x7FFFu + ((v.u >> 16) & 1u);
  return (short)(r >> 16);
}

__device__ __forceinline__ unsigned cvt_pk_bf16(float lo, float hi) {
  unsigned r;
  asm("v_cvt_pk_bf16_f32 %0, %1, %2" : "=v"(r) : "v"(lo), "v"(hi));
  return r;
}

__device__ __forceinline__ f32x4 mfma16(bf16x8 a, bf16x8 b, f32x4 c) {
  return __builtin_amdgcn_mfma_f32_16x16x32_bf16(a, b, c, 0, 0, 0);
}

// ---------------------------------------------------------------------------
// Kernel 1: fold value-path weights (unchanged).
// ---------------------------------------------------------------------------
__global__ void k_fuse(const float* __restrict__ wq, const float* __restrict__ wk,
                       const float* __restrict__ wv, const float* __restrict__ weight,
                       const float* __restrict__ bv,
                       short* __restrict__ wqb, short* __restrict__ wkb,
                       short* __restrict__ wfT, float* __restrict__ bfu) {
  int u = blockIdx.x, c = threadIdx.x;
  float acc = 0.f;
  for (int o = 0; o < OUTC; ++o) acc += wv[o * CIN + c] * weight[o * OUTC + u];
  wfT[u * CIN + c] = f2bf(acc);
  if (u < C4D) {
    wqb[u * CIN + c] = f2bf(wq[u * CIN + c]);
    wkb[u * CIN + c] = f2bf(wk[u * CIN + c]);
  }
  if (c == 0) {
    float a = 0.f;
    for (int o = 0; o < OUTC; ++o) a += bv[o] * weight[o * OUTC + u];
    bfu[u] = a;
  }
}

// ---------------------------------------------------------------------------
// Kernel 2: projections (unchanged from R8). Fragment-linear QL / VF tiles,
// VF stores vectorized via cvt_pk + uint2.
// ---------------------------------------------------------------------------
__global__ __launch_bounds__(256) void k_proj(
    const float* __restrict__ x, const float* __restrict__ bq, const float* __restrict__ bk,
    const short* __restrict__ wqb, const short* __restrict__ wkb,
    const short* __restrict__ wfT, const float* __restrict__ bfu,
    short* __restrict__ ql, short* __restrict__ kb, short* __restrict__ vfb) {
  const int wid = threadIdx.x >> 6, lane = threadIdx.x & 63;
  const int lo = lane & 15, g = lane >> 4;
  const int p0 = blockIdx.x * 64 + wid * 16;

  f32x4 aq[2] = {}, ak[2] = {}, as_[8] = {};

#pragma unroll
  for (int kk = 0; kk < 4; ++kk) {
    const float* xp = x + (size_t)(p0 + lo) * CIN + kk * 32 + g * 8;
    float4 xa = *(const float4*)xp;
    float4 xb = *(const float4*)(xp + 4);
    bf16x8 af;
    af[0] = f2bf(xa.x); af[1] = f2bf(xa.y); af[2] = f2bf(xa.z); af[3] = f2bf(xa.w);
    af[4] = f2bf(xb.x); af[5] = f2bf(xb.y); af[6] = f2bf(xb.z); af[7] = f2bf(xb.w);
#pragma unroll
    for (int n = 0; n < 2; ++n) {
      bf16x8 bq_ = *(const bf16x8*)(wqb + (size_t)(n * 16 + lo) * CIN + kk * 32 + g * 8);
      aq[n] = mfma16(af, bq_, aq[n]);
      bf16x8 bk_ = *(const bf16x8*)(wkb + (size_t)(n * 16 + lo) * CIN + kk * 32 + g * 8);
      ak[n] = mfma16(af, bk_, ak[n]);
    }
#pragma unroll
    for (int n = 0; n < 8; ++n) {
      bf16x8 bs = *(const bf16x8*)(wfT + (size_t)(n * 16 + lo) * CIN + kk * 32 + g * 8);
      as_[n] = mfma16(af, bs, as_[n]);
    }
  }

#pragma unroll
  for (int n = 0; n < 2; ++n) {
    float bqv = bq[n * 16 + lo], bkv = bk[n * 16 + lo];
    int u = n * 16 + lo;
#pragma unroll
    for (int r = 0; r < 4; ++r) {
      int p = p0 + 4 * g + r;
      int bb = p >> 12, s = p & (SEQ - 1);
      ql[(size_t)bb * (SEQ * 32) + (size_t)(s >> 5) * 1024 + ((s >> 4) & 1) * 512 +
         (u >> 3) * 128 + (s & 15) * 8 + (u & 7)] = f2bf(aq[n][r] + bqv);
      kb[(size_t)p * C4D + u] = f2bf(ak[n][r] + bkv);
    }
  }
  {
    const int p = p0 + 4 * g;          // r = 0; r=0..3 contiguous in VF
    const int bb = p >> 12, s = p & (SEQ - 1);
#pragma unroll
    for (int n = 0; n < 8; ++n) {
      int u = n * 16 + lo;
      float bvv = bfu[u];
      uint2 w;
      w.x = cvt_pk_bf16(as_[n][0] + bvv, as_[n][1] + bvv);
      w.y = cvt_pk_bf16(as_[n][2] + bvv, as_[n][3] + bvv);
      *(uint2*)&vfb[(size_t)bb * (SEQ * 128) + (size_t)(s >> 5) * 4096 + (u >> 4) * 512 +
                    ((s >> 2) & 3) * 128 + (u & 15) * 8 + ((s >> 4) & 1) * 4] = w;
    }
  }
}

// ---------------------------------------------------------------------------
// Kernel 3 (Design II): wave = 64 i-rows (4 K-frags, o[4][8] acc), block =
// 8 waves sharing the same 64 rows, j-split 8 (512 j / wave, 16 iters).
// Each V-fragment feeds 4 MFMAs. Defer-max softmax (rare rescale), deferred
// l-reduce, cvt_pk. 3-round LDS tree merge (4 x 32KB slots). XCD swizzle.
// ---------------------------------------------------------------------------
__global__ __launch_bounds__(512, 2) void k_attn(
    const short* __restrict__ ql, const short* __restrict__ kb,
    const short* __restrict__ vfb, const float* __restrict__ bias,
    float* __restrict__ out) {
  const int tid = threadIdx.x;
  const int wid = tid >> 6, lane = tid & 63;
  const int lo = lane & 15, g = lane >> 4;
  const int bid = blockIdx.x;
  const int xb = ((bid & 7) << 5) | (bid >> 3);   // 256 blocks, bijective
  const int b = xb >> 6;
  const int iw = (xb & 63) * 64;

  __shared__ float LDSF[33280];   // 4 slots x 8192 (O) + 4x64 (M) + 4x64 (L)

  const short* qB = ql + (size_t)b * (SEQ * 32) + (size_t)wid * 16384;
  const short* vB = vfb + (size_t)b * (SEQ * 128) + (size_t)wid * 65536;

  bf16x8 kf[4];
#pragma unroll
  for (int c = 0; c < 4; ++c)
    kf[c] = *(const bf16x8*)(kb + (size_t)(b * SEQ + iw + 16 * c + lo) * C4D + g * 8);

  f32x4 o[4][8];
#pragma unroll
  for (int c = 0; c < 4; ++c)
#pragma unroll
    for (int n = 0; n < 8; ++n) o[c][n] = (f32x4){0.f, 0.f, 0.f, 0.f};

  float ma[4] = {-3e38f, -3e38f, -3e38f, -3e38f};
  float la[4] = {0.f, 0.f, 0.f, 0.f};
  const f32x4 zf = {0.f, 0.f, 0.f, 0.f};

  bf16x8 pf[4];

  for (int t = 0; t < 16; ++t) {
    const short* qt = qB + t * 1024;
    bf16x8 qf0 = *(const bf16x8*)(qt + lane * 8);
    bf16x8 qf1 = *(const bf16x8*)(qt + 512 + lane * 8);

    f32x4 s0[4], s1[4];
    float tm[4];
#pragma unroll
    for (int c = 0; c < 4; ++c) {
      s0[c] = mfma16(qf0, kf[c], zf);
      s1[c] = mfma16(qf1, kf[c], zf);
      tm[c] = fmaxf(fmaxf(fmaxf(s0[c][0], s0[c][1]), fmaxf(s0[c][2], s0[c][3])),
                    fmaxf(fmaxf(s1[c][0], s1[c][1]), fmaxf(s1[c][2], s1[c][3])));
    }
    bool need = (tm[0] > ma[0] + 8.f) | (tm[1] > ma[1] + 8.f) |
                (tm[2] > ma[2] + 8.f) | (tm[3] > ma[3] + 8.f);
    if (__any(need)) {
#pragma unroll
      for (int c = 0; c < 4; ++c) {
        float rowm = fmaxf(tm[c], __shfl_xor(tm[c], 16, 64));
        rowm = fmaxf(rowm, __shfl_xor(rowm, 32, 64));
        float mnew = fmaxf(ma[c], rowm);
        float scale = __expf(ma[c] - mnew);
        la[c] *= scale;
        float sc[4];
#pragma unroll
        for (int r = 0; r < 4; ++r) sc[r] = __shfl(scale, 4 * g + r, 64);
#pragma unroll
        for (int n = 0; n < 8; ++n)
#pragma unroll
          for (int r = 0; r < 4; ++r) o[c][n][r] *= sc[r];
        ma[c] = mnew;
      }
    }

#pragma unroll
    for (int c = 0; c < 4; ++c) {
      float p[8];
#pragma unroll
      for (int r = 0; r < 4; ++r) {
        p[r]     = __expf(s0[c][r] - ma[c]);
        p[4 + r] = __expf(s1[c][r] - ma[c]);
      }
      la[c] += (p[0] + p[1]) + (p[2] + p[3]) + ((p[4] + p[5]) + (p[6] + p[7]));
      union { bf16x8 v8; unsigned u[4]; } pk;
      pk.u[0] = cvt_pk_bf16(p[0], p[1]);
      pk.u[1] = cvt_pk_bf16(p[2], p[3]);
      pk.u[2] = cvt_pk_bf16(p[4], p[5]);
      pk.u[3] = cvt_pk_bf16(p[6], p[7]);
      pf[c] = pk.v8;
    }

    const short* vt = vB + t * 4096;
#pragma unroll
    for (int n = 0; n < 8; ++n) {
      bf16x8 vfr = *(const bf16x8*)(vt + n * 512 + lane * 8);
      o[0][n] = mfma16(pf[0], vfr, o[0][n]);
      o[1][n] = mfma16(pf[1], vfr, o[1][n]);
      o[2][n] = mfma16(pf[2], vfr, o[2][n]);
      o[3][n] = mfma16(pf[3], vfr, o[3][n]);
    }
  }

  // deferred l-reduce over g (each g covered distinct j)
#pragma unroll
  for (int c = 0; c < 4; ++c) {
    la[c] += __shfl_xor(la[c], 16, 64);
    la[c] += __shfl_xor(la[c], 32, 64);
  }

  auto write_slot = [&](int s) {
    float* OSs = LDSF + s * 8192;
#pragma unroll
    for (int c = 0; c < 4; ++c)
#pragma unroll
      for (int n = 0; n < 8; ++n)
        *(f32x4*)&OSs[(c * 8 + n) * 256 + lane * 4] = o[c][n];
    if (lane < 16) {
#pragma unroll
      for (int c = 0; c < 4; ++c) {
        LDSF[32768 + s * 64 + c * 16 + lo] = ma[c];
        LDSF[33024 + s * 64 + c * 16 + lo] = la[c];
      }
    }
  };
  auto merge_slot = [&](int s) {
    float* OSs = LDSF + s * 8192;
#pragma unroll
    for (int c = 0; c < 4; ++c) {
      float ms = LDSF[32768 + s * 64 + c * 16 + lo];
      float ls = LDSF[33024 + s * 64 + c * 16 + lo];
      float M = fmaxf(ma[c], ms);
      float eo = __expf(ma[c] - M), es = __expf(ms - M);
      la[c] = eo * la[c] + es * ls;
      ma[c] = M;
      float eor[4], esr[4];
#pragma unroll
      for (int r = 0; r < 4; ++r) {
        eor[r] = __shfl(eo, 4 * g + r, 64);
        esr[r] = __shfl(es, 4 * g + r, 64);
      }
#pragma unroll
      for (int n = 0; n < 8; ++n) {
        f32x4 v = *(f32x4*)&OSs[(c * 8 + n) * 256 + lane * 4];
#pragma unroll
        for (int r = 0; r < 4; ++r)
          o[c][n][r] = eor[r] * o[c][n][r] + esr[r] * v[r];
      }
    }
  };

  if (wid >= 4) write_slot(wid - 4);
  __syncthreads();
  if (wid < 4) merge_slot(wid);
  __syncthreads();
  if (wid == 1) write_slot(0);
  if (wid == 3) write_slot(1);
  __syncthreads();
  if (wid == 0) merge_slot(0);
  if (wid == 2) merge_slot(1);
  __syncthreads();
  if (wid == 2) write_slot(0);
  __syncthreads();
  if (wid == 0) {
    merge_slot(0);
    float* outp = out + (size_t)(b * SEQ + iw) * OUTC;
#pragma unroll
    for (int c = 0; c < 4; ++c) {
      float ia = 1.f / la[c];
      float lir[4];
#pragma unroll
      for (int r = 0; r < 4; ++r) lir[r] = __shfl(ia, 4 * g + r, 64);
#pragma unroll
      for (int n = 0; n < 8; ++n) {
        float bu = bias[n * 16 + lo];
#pragma unroll
        for (int r = 0; r < 4; ++r)
          outp[(size_t)(c * 16 + 4 * g + r) * OUTC + n * 16 + lo] =
              o[c][n][r] * lir[r] + bu;
      }
    }
  }
}

// ---------------------------------------------------------------------------
extern "C" void kernel_launch(void* const* d_in, const int* in_sizes, int n_in,
                              void* d_out, int out_size, void* d_ws, size_t ws_size,
                              hipStream_t stream) {
  (void)in_sizes; (void)n_in; (void)out_size; (void)ws_size;
  const float* x      = (const float*)d_in[0];
  const float* weight = (const float*)d_in[1];
  const float* bias   = (const float*)d_in[2];
  const float* wq     = (const float*)d_in[3];
  const float* bq     = (const float*)d_in[4];
  const float* wk     = (const float*)d_in[5];
  const float* bk     = (const float*)d_in[6];
  const float* wv     = (const float*)d_in[7];
  const float* bv     = (const float*)d_in[8];
  float* out = (float*)d_out;

  char* ws = (char*)d_ws;
  short* kbuf = (short*)(ws);                                   // 1 MiB [p][32]
  short* vfb  = (short*)(ws + ((size_t)1 << 20));               // 4 MiB VF tiles
  short* qlb  = (short*)(ws + ((size_t)5 << 20));               // 1 MiB QL tiles
  short* wqb  = (short*)(ws + ((size_t)6 << 20));               // 8 KiB
  short* wkb  = (short*)(ws + ((size_t)6 << 20) + 8192);        // 8 KiB
  short* wfT  = (short*)(ws + ((size_t)6 << 20) + 16384);       // 32 KiB
  float* bfu  = (float*)(ws + ((size_t)6 << 20) + 49152);       // 512 B

  hipLaunchKernelGGL(k_fuse, dim3(OUTC), dim3(CIN), 0, stream,
                     wq, wk, wv, weight, bv, wqb, wkb, wfT, bfu);
  hipLaunchKernelGGL(k_proj, dim3(NB * SEQ / 64), dim3(256), 0, stream,
                     x, bq, bk, wqb, wkb, wfT, bfu, qlb, kbuf, vfb);
  hipLaunchKernelGGL(k_attn, dim3(NB * SEQ / 64), dim3(512), 0, stream,
                     qlb, kbuf, vfb, bias, out);
}